// Round 5
// baseline (119.610 us; speedup 1.0000x reference)
//
#include <hip/hip_runtime.h>
#include <hip/hip_bf16.h>
#include <hip/hip_fp16.h>

// Problem constants
#define BATCH 256
#define IN_DIM 1024
#define NKER 100
#define DKER 50
#define ACT_N 5000           // NKER*DKER
#define OUT_DIM 1124         // IN_DIM + NKER

typedef short bf16x8 __attribute__((ext_vector_type(8)));
typedef float f32x4v __attribute__((ext_vector_type(4)));
typedef _Float16 h2 __attribute__((ext_vector_type(2)));

// ============ Kernel 1: bf16 MFMA GEMM  act = x @ W  (fp32 in, fp16 out) ============
// 512 threads (8 waves), tile 32(M) x 64(N), BK=128, grid 79x8=632 (~2.5 blk/CU,
// ~5 waves/SIMD). Round-4 defect: VGPR_Count=36 proved the compiler SANK the
// register-prefetch loads past __syncthreads to their use (legal: __restrict__
// read-only), re-serializing HBM latency every iteration. sched_barrier(0)
// right after the prefetch block pins the loads in the MFMA-overlap window.
#define BKK 128
#define LDSB 136   // bf16 row stride; b128 at stride 68 words hits the 8-pass wave floor (optimal)

__global__ __launch_bounds__(512) void gemm_bf16_kernel(const float* __restrict__ X,
                                                        const float* __restrict__ W,
                                                        __half* __restrict__ act) {
    constexpr int K = IN_DIM, N = ACT_N;
    __shared__ __attribute__((aligned(16))) __hip_bfloat16 As[32 * LDSB];
    __shared__ __attribute__((aligned(16))) __hip_bfloat16 Bs[64 * LDSB];

    const int tid = threadIdx.x;
    // XCD swizzle: 8 m-blocks sharing one W column-slice -> same XCD -> L2 reuse.
    const int id = blockIdx.x;                       // grid 640, 8 idle
    const int bx = (id & 7) + ((id >> 6) << 3);      // 0..79
    const int bm = (id >> 3) & 7;                    // 0..7
    if (bx >= 79) return;
    const int m0 = bm * 32, n0 = bx * 64;

    const int am = tid >> 4, aseg = tid & 15;        // A: row 0..31, 8-k segment
    const int bn = tid & 63, bseg = tid >> 6;        // B: col 0..63, 16-k segment
    const bool bvalid = (n0 + bn) < N;

    const int lane = tid & 63, w = tid >> 6;
    const int wm = (w & 1) * 16, wn = (w >> 1) * 16;
    const int fl = lane & 15, fq = lane >> 4;

    f32x4v acc = {0.f, 0.f, 0.f, 0.f};

    const float* Xp = X + (m0 + am) * K + aseg * 8;
    const float* Wp = W + (bseg * 16) * N + n0 + bn;

    // ---- prefetch iteration 0 ----
    float4 a0 = *(const float4*)(Xp + 0);
    float4 a1 = *(const float4*)(Xp + 4);
    float bv[16];
    #pragma unroll
    for (int j = 0; j < 16; ++j) bv[j] = bvalid ? Wp[j * N] : 0.f;

    for (int k0 = 0; k0 < K; k0 += BKK) {
        __syncthreads();   // all waves done reading LDS of previous iteration

        // ---- cvt fp32->bf16, stage regs -> LDS ----
        __hip_bfloat16 at[8];
        at[0]=__float2bfloat16(a0.x); at[1]=__float2bfloat16(a0.y); at[2]=__float2bfloat16(a0.z); at[3]=__float2bfloat16(a0.w);
        at[4]=__float2bfloat16(a1.x); at[5]=__float2bfloat16(a1.y); at[6]=__float2bfloat16(a1.z); at[7]=__float2bfloat16(a1.w);
        *(bf16x8*)&As[am * LDSB + aseg * 8] = *(const bf16x8*)&at[0];

        __hip_bfloat16 bt[16];
        #pragma unroll
        for (int j = 0; j < 16; ++j) bt[j] = __float2bfloat16(bv[j]);
        *(bf16x8*)&Bs[bn * LDSB + bseg * 16 + 0] = *(const bf16x8*)&bt[0];
        *(bf16x8*)&Bs[bn * LDSB + bseg * 16 + 8] = *(const bf16x8*)&bt[8];
        __syncthreads();

        // ---- issue next iteration's loads; sched_barrier pins them HERE ----
        if (k0 + BKK < K) {
            const float* Xn = Xp + k0 + BKK;
            a0 = *(const float4*)(Xn + 0);
            a1 = *(const float4*)(Xn + 4);
            const float* Wn = Wp + (k0 + BKK) * N;
            #pragma unroll
            for (int j = 0; j < 16; ++j) bv[j] = bvalid ? Wn[j * N] : 0.f;
            __builtin_amdgcn_sched_barrier(0);   // forbid sinking loads below this point
        }

        // ---- MFMA: 4 k-steps of 32, single 16x16 frag per wave ----
        #pragma unroll
        for (int kk = 0; kk < BKK; kk += 32) {
            bf16x8 af = *(const bf16x8*)&As[(wm + fl) * LDSB + kk + fq * 8];
            bf16x8 bf = *(const bf16x8*)&Bs[(wn + fl) * LDSB + kk + fq * 8];
            acc = __builtin_amdgcn_mfma_f32_16x16x32_bf16(af, bf, acc, 0, 0, 0);
        }
    }

    // ---- epilogue: C/D layout col = lane&15, row = (lane>>4)*4 + reg ----
    const int row0 = m0 + wm + fq * 4;
    const int col0 = n0 + wn + fl;
    if (col0 < N) {
        #pragma unroll
        for (int r = 0; r < 4; ++r) act[(row0 + r) * N + col0] = __float2half(acc[r]);
    }
}

// ============ Kernel 2: pairwise L1 -> exp -> sum -> partial features ============
// Precision: only the diagonal matters (|a-a|=0 -> exp(0)=1, exact in fp16);
// off-diagonal exp(-l1) ~ 1e-31. Packed-fp16 |diff| accumulation is exact on
// the diagonal and full-rate VALU (round-4 used 56 fdot2/lane/jj, suspected
// quarter-rate; now 2 fdot2 per jj).
// grid (100 k, 2 i-half, 2 j-half) = 400 blocks, 256 threads (4 waves).
// Block: 128 i x 128 j; lane holds 2 rows; wave j-slice -> wave-uniform
// broadcast ds_read_b128, 7 reads serve 128 (i,j) pairs.
#define PKACC(r, m, acc) { h2 dd = __builtin_bit_cast(h2, (uint)(m)) - __builtin_bit_cast(h2, (uint)(r)); \
    uint uu = __builtin_bit_cast(uint, dd) & 0x7FFF7FFFu;                                                \
    acc = acc + __builtin_bit_cast(h2, uu); }

__global__ __launch_bounds__(256) void pairwise_kernel(const __half* __restrict__ act,
                                                       float* __restrict__ part) {
    const int k  = blockIdx.x;
    const int ib = blockIdx.y * 128;        // i-half base
    const int jb = blockIdx.z * 128;        // j-half base
    __shared__ __attribute__((aligned(16))) __half S[256 * 56];   // 28672 B
    __shared__ float P[4 * 128];
    const int tid = threadIdx.x;

    // stage act[:, k*50 : +50] as fp16, zero-padded to 56 halves/row
    const ushort* __restrict__ src = (const ushort*)act + k * DKER;
    for (int idx = tid; idx < 256 * 32; idx += 256) {
        const int j = idx >> 5, d = idx & 31;
        if (d < 28) {
            uint v = 0u;
            if (d < 25) v = *(const uint*)(src + j * ACT_N + d * 2);
            *(uint*)&S[j * 56 + d * 2] = v;
        }
    }
    __syncthreads();

    const int lane = tid & 63, w = tid >> 6;

    uint my1[28], my2[28];
    {
        const uint* r1 = (const uint*)&S[(ib + lane) * 56];
        const uint* r2 = (const uint*)&S[(ib + 64 + lane) * 56];
        #pragma unroll
        for (int d = 0; d < 28; ++d) { my1[d] = r1[d]; my2[d] = r2[d]; }
    }

    const h2 kOne = { (_Float16)1.0f, (_Float16)1.0f };
    float sA = 0.f, sB = 0.f;
    const int j0 = jb + w * 32;
    for (int jj = 0; jj < 32; ++jj) {
        const uint4* row4 = (const uint4*)&S[(j0 + jj) * 56];   // uniform across wave
        h2 cA0 = {0, 0}, cA1 = {0, 0}, cB0 = {0, 0}, cB1 = {0, 0};
        #pragma unroll
        for (int q = 0; q < 7; ++q) {
            const uint4 rv = row4[q];
            PKACC(rv.x, my1[4*q+0], cA0) PKACC(rv.y, my1[4*q+1], cA1)
            PKACC(rv.z, my1[4*q+2], cA0) PKACC(rv.w, my1[4*q+3], cA1)
            PKACC(rv.x, my2[4*q+0], cB0) PKACC(rv.y, my2[4*q+1], cB1)
            PKACC(rv.z, my2[4*q+2], cB0) PKACC(rv.w, my2[4*q+3], cB1)
        }
        const float l1A = __builtin_amdgcn_fdot2(cA0 + cA1, kOne, 0.f, false);
        const float l1B = __builtin_amdgcn_fdot2(cB0 + cB1, kOne, 0.f, false);
        sA += __expf(-l1A);
        sB += __expf(-l1B);
    }

    P[w * 128 + lane]      = sA;
    P[w * 128 + 64 + lane] = sB;
    __syncthreads();
    if (tid < 128) {
        float f = 0.f;
        #pragma unroll
        for (int g = 0; g < 4; ++g) f += P[g * 128 + tid];
        // partial layout: part[((k*2 + jh)*2 + ih)*128 + il]
        part[((k * 2 + blockIdx.z) * 2 + blockIdx.y) * 128 + tid] = f;
    }
}

// ============ Kernel 3: copy x + combine j-half partials into out ============
// grid 256 (one block per row i), 256 threads.
__global__ __launch_bounds__(256) void combine_kernel(const float* __restrict__ x,
                                                      const float* __restrict__ part,
                                                      float* __restrict__ out) {
    const int i = blockIdx.x;
    const int t = threadIdx.x;
    // copy x row
    *(float4*)&out[i * OUT_DIM + t * 4] = *(const float4*)&x[i * IN_DIM + t * 4];
    // features
    if (t < NKER) {
        const int ih = i >> 7, il = i & 127;
        const float f = part[((t * 2 + 0) * 2 + ih) * 128 + il]
                      + part[((t * 2 + 1) * 2 + ih) * 128 + il];
        out[i * OUT_DIM + IN_DIM + t] = f;
    }
}

extern "C" void kernel_launch(void* const* d_in, const int* in_sizes, int n_in,
                              void* d_out, int out_size, void* d_ws, size_t ws_size,
                              hipStream_t stream) {
    const float* x = (const float*)d_in[0];       // 256x1024
    const float* w = (const float*)d_in[1];       // 1024x5000
    float* out = (float*)d_out;                   // 256x1124
    __half* act = (__half*)d_ws;                  // 256x5000 fp16 (2.56 MB)
    float* part = (float*)((char*)d_ws + (4 << 20));   // 100*2*2*128 fp32 partials

    gemm_bf16_kernel<<<dim3(640), dim3(512), 0, stream>>>(x, w, act);
    pairwise_kernel<<<dim3(NKER, 2, 2), dim3(256), 0, stream>>>(act, part);
    combine_kernel<<<dim3(256), dim3(256), 0, stream>>>(x, part, out);
}